// Round 2
// baseline (212.946 us; speedup 1.0000x reference)
//
#include <hip/hip_runtime.h>
#include <hip/hip_bf16.h>

// Dtypes (per reference + harness contract): z/W1/b1/W2/b2 are float32,
// edge is int32 ("integer -> const int*"), output is float32.
// Round-1 NaN post-mortem: reading the f32 inputs as bf16 produced bf16-NaN
// bit patterns (~0.4%/element) -> NaN flood. Threshold 1.484e-2 == 2% of ref
// absmax 0.742 (relative), so in-kernel bf16 MFMA compute is safely inside it.

#define N_EDGES 500000
#define D_IN    128
#define D_HID   256

#define M_TILE     64
#define LDS_STRIDE 136   // 128 + 8 bf16 pad -> <=2-way LDS bank aliasing (free)

typedef __bf16 bf16x8 __attribute__((ext_vector_type(8)));
typedef float  f32x4  __attribute__((ext_vector_type(4)));

__device__ __forceinline__ unsigned short f2bf(float f) {
    union { float f; unsigned int u; } c; c.f = f;
    unsigned int u = c.u;
    return (unsigned short)((u + 0x7fffu + ((u >> 16) & 1u)) >> 16);  // RNE
}

// mish(x) = x * tanh(softplus(x)) = x * N/(N+2),  N = E*(E+2), E = e^x (exact)
__device__ __forceinline__ float mish_f(float x) {
    float xc  = fminf(x, 20.0f);           // tanh(sp(x))==1 beyond; avoids inf*0
    float E   = __expf(xc);
    float num = E * (E + 2.0f);
    return x * num * __builtin_amdgcn_rcpf(num + 2.0f);
}

__global__ __launch_bounds__(256, 2)
void edge_decoder_kernel(const float* __restrict__ z,
                         const int*   __restrict__ edge,
                         const float* __restrict__ W1,
                         const float* __restrict__ b1,
                         const float* __restrict__ W2,
                         const float* __restrict__ b2,
                         float*       __restrict__ out,
                         int ntiles) {
    __shared__ ushort xbuf[M_TILE * LDS_STRIDE];
    __shared__ float  lpart[4][M_TILE];

    const int t    = threadIdx.x;
    const int wave = t >> 6;
    const int lane = t & 63;
    const int quad = lane >> 4;
    const int nlo  = lane & 15;

    // ---- W1 -> bf16 B-fragments + b1/W2 slices, loaded once into registers ----
    // wave w owns hidden cols [64w, 64w+64). B[k][n]=W1[n][k]; lane: n=nlo+16nt, k=32ks+8quad+j
    bf16x8 bfrag[4][4];   // [ks][nt]
    float  b1f[4], w2f[4];
    {
        #pragma unroll
        for (int nt = 0; nt < 4; ++nt) {
            const int n = wave * 64 + nt * 16 + nlo;
            const float* wrow = W1 + n * D_IN;
            #pragma unroll
            for (int ks = 0; ks < 4; ++ks) {
                const float* wp = wrow + ks * 32 + quad * 8;
                float4 w0 = *reinterpret_cast<const float4*>(wp);
                float4 w1 = *reinterpret_cast<const float4*>(wp + 4);
                union { unsigned short s[8]; bf16x8 v; } u;
                u.s[0] = f2bf(w0.x); u.s[1] = f2bf(w0.y);
                u.s[2] = f2bf(w0.z); u.s[3] = f2bf(w0.w);
                u.s[4] = f2bf(w1.x); u.s[5] = f2bf(w1.y);
                u.s[6] = f2bf(w1.z); u.s[7] = f2bf(w1.w);
                bfrag[ks][nt] = u.v;
            }
            b1f[nt] = b1[n];
            w2f[nt] = W2[n];
        }
    }
    const float b2f = b2[0];

    const int gc = t & 15;   // column chunk of 8 floats
    const int gs = t >> 4;   // edge slot within group of 16

    for (int tile = blockIdx.x; tile < ntiles; tile += gridDim.x) {
        const int ebase = tile * M_TILE;

        // ---- gather x = z[u]*z[v], cvt bf16 -> LDS ----
        #pragma unroll
        for (int it = 0; it < 4; ++it) {
            const int el = it * 16 + gs;
            int e = ebase + el;
            e = min(e, N_EDGES - 1);
            const int u = edge[e];
            const int v = edge[N_EDGES + e];
            const float* zu = z + (size_t)u * D_IN + gc * 8;
            const float* zv = z + (size_t)v * D_IN + gc * 8;
            float4 a0 = *reinterpret_cast<const float4*>(zu);
            float4 a1 = *reinterpret_cast<const float4*>(zu + 4);
            float4 c0 = *reinterpret_cast<const float4*>(zv);
            float4 c1 = *reinterpret_cast<const float4*>(zv + 4);
            unsigned int r0 = (unsigned int)f2bf(a0.x * c0.x) | ((unsigned int)f2bf(a0.y * c0.y) << 16);
            unsigned int r1 = (unsigned int)f2bf(a0.z * c0.z) | ((unsigned int)f2bf(a0.w * c0.w) << 16);
            unsigned int r2 = (unsigned int)f2bf(a1.x * c1.x) | ((unsigned int)f2bf(a1.y * c1.y) << 16);
            unsigned int r3 = (unsigned int)f2bf(a1.z * c1.z) | ((unsigned int)f2bf(a1.w * c1.w) << 16);
            *reinterpret_cast<uint4*>(&xbuf[el * LDS_STRIDE + gc * 8]) =
                make_uint4(r0, r1, r2, r3);
        }
        __syncthreads();

        // ---- MFMA: h[64 x 64(this wave)] = x @ W1^T ----
        f32x4 acc[4][4];   // [mt][nt]
        #pragma unroll
        for (int mt = 0; mt < 4; ++mt)
            #pragma unroll
            for (int nt = 0; nt < 4; ++nt)
                acc[mt][nt] = (f32x4){0.f, 0.f, 0.f, 0.f};

        #pragma unroll
        for (int ks = 0; ks < 4; ++ks) {
            bf16x8 afrag[4];
            #pragma unroll
            for (int mt = 0; mt < 4; ++mt)
                afrag[mt] = *reinterpret_cast<const bf16x8*>(
                    &xbuf[(mt * 16 + nlo) * LDS_STRIDE + ks * 32 + quad * 8]);
            #pragma unroll
            for (int mt = 0; mt < 4; ++mt)
                #pragma unroll
                for (int nt = 0; nt < 4; ++nt)
                    acc[mt][nt] = __builtin_amdgcn_mfma_f32_16x16x32_bf16(
                        afrag[mt], bfrag[ks][nt], acc[mt][nt], 0, 0, 0);
        }

        // ---- epilogue: +b1, mish, dot W2 slice, reduce 16 lanes ----
        // D layout: row = mt*16 + quad*4 + r, col = nlo + 16*nt (+64*wave)
        #pragma unroll
        for (int mt = 0; mt < 4; ++mt) {
            #pragma unroll
            for (int r = 0; r < 4; ++r) {
                float s = 0.f;
                #pragma unroll
                for (int nt = 0; nt < 4; ++nt) {
                    float h = acc[mt][nt][r] + b1f[nt];
                    s += mish_f(h) * w2f[nt];
                }
                s += __shfl_xor(s, 1);
                s += __shfl_xor(s, 2);
                s += __shfl_xor(s, 4);
                s += __shfl_xor(s, 8);
                if (nlo == 0) lpart[wave][mt * 16 + quad * 4 + r] = s;
            }
        }
        __syncthreads();

        // ---- combine 4 waves, sigmoid, store f32 ----
        if (t < M_TILE) {
            const int e = ebase + t;
            if (e < N_EDGES) {
                float logit = lpart[0][t] + lpart[1][t] + lpart[2][t] + lpart[3][t] + b2f;
                out[e] = __builtin_amdgcn_rcpf(1.0f + __expf(-logit));
            }
        }
        // lpart reads complete before the next post-gather barrier; xbuf next-iter
        // writes are ordered after the barrier above -> no races
    }
}

extern "C" void kernel_launch(void* const* d_in, const int* in_sizes, int n_in,
                              void* d_out, int out_size, void* d_ws, size_t ws_size,
                              hipStream_t stream) {
    const float* z    = (const float*)d_in[0];
    const int*   edge = (const int*)d_in[1];
    const float* W1   = (const float*)d_in[2];
    const float* b1   = (const float*)d_in[3];
    const float* W2   = (const float*)d_in[4];
    const float* b2   = (const float*)d_in[5];
    float* out = (float*)d_out;

    const int ntiles = (N_EDGES + M_TILE - 1) / M_TILE;  // 7813
    const int grid   = 2048;                             // grid-stride
    edge_decoder_kernel<<<dim3(grid), dim3(256), 0, stream>>>(z, edge, W1, b1, W2, b2, out, ntiles);
}

// Round 3
// 177.665 us; speedup vs baseline: 1.1986x; 1.1986x over previous
//
#include <hip/hip_runtime.h>
#include <hip/hip_bf16.h>

// f32 in / f32 out; bf16 MFMA inside (threshold is 2% relative; absmax was 3.9e-3).
// Round-3 restructure: software-pipelined gather (edge idx prefetched 2 tiles
// ahead, z rows 1 tile ahead), double-buffered LDS, ONE barrier per tile,
// 512-thread blocks with 32 hidden cols per wave (bfrag 32 VGPR, acc 16).

#define N_EDGES 500000
#define D_IN    128
#define D_HID   256
#define M_TILE  32
#define NTILES  (N_EDGES / M_TILE)   // 15625 exactly, no partial tile
#define LDS_STRIDE 136               // 128 + 8 bf16 pad
#define GRID    512                  // 2 blocks/CU resident target

typedef __bf16 bf16x8 __attribute__((ext_vector_type(8)));
typedef float  f32x4  __attribute__((ext_vector_type(4)));
typedef float  f32x2  __attribute__((ext_vector_type(2)));

union F4H { float4 v; f32x2 h[2]; };

__device__ __forceinline__ unsigned int pkbf(f32x2 q) {
    union { __hip_bfloat162 b; unsigned int u; } c;
    c.b = __float22bfloat162_rn(make_float2(q.x, q.y));   // RNE packed cvt
    return c.u;
}

// mish(x) = x * N/(N+2), N = E*(E+2), E = e^x — float2-vectorized, scalar exp/rcp
__device__ __forceinline__ f32x2 mish2(f32x2 x) {
    f32x2 xc = {fminf(x.x, 20.0f), fminf(x.y, 20.0f)};
    f32x2 E  = {__expf(xc.x), __expf(xc.y)};
    f32x2 num = E * (E + 2.0f);
    f32x2 den = num + 2.0f;
    f32x2 r  = {__builtin_amdgcn_rcpf(den.x), __builtin_amdgcn_rcpf(den.y)};
    return x * num * r;
}

__global__ __launch_bounds__(512, 4)
void edge_decoder_kernel(const float* __restrict__ z,
                         const int*   __restrict__ edge,
                         const float* __restrict__ W1,
                         const float* __restrict__ b1,
                         const float* __restrict__ W2,
                         const float* __restrict__ b2,
                         float*       __restrict__ out) {
    __shared__ ushort xbuf[2][M_TILE * LDS_STRIDE];   // 2 x 8.7 KB
    __shared__ float  lpart[2][8][M_TILE];            // 2 KB

    const int t    = threadIdx.x;
    const int wave = t >> 6;          // 0..7
    const int lane = t & 63;
    const int quad = lane >> 4;
    const int nlo  = lane & 15;

    // ---- W1 -> bf16 B-fragments (wave owns hidden cols [32w, 32w+32)) ----
    bf16x8 bfrag[4][2];               // [ks][nt] = 32 VGPRs
    float  b1f[2], w2f[2];
    #pragma unroll
    for (int nt = 0; nt < 2; ++nt) {
        const int n = wave * 32 + nt * 16 + nlo;
        const float* wrow = W1 + n * D_IN;
        #pragma unroll
        for (int ks = 0; ks < 4; ++ks) {
            F4H w0, w1;
            w0.v = *reinterpret_cast<const float4*>(wrow + ks * 32 + quad * 8);
            w1.v = *reinterpret_cast<const float4*>(wrow + ks * 32 + quad * 8 + 4);
            union { unsigned int u[4]; bf16x8 v; } o;
            o.u[0] = pkbf(w0.h[0]); o.u[1] = pkbf(w0.h[1]);
            o.u[2] = pkbf(w1.h[0]); o.u[3] = pkbf(w1.h[1]);
            bfrag[ks][nt] = o.v;
        }
        b1f[nt] = b1[n];
        w2f[nt] = W2[n];
    }
    const float b2f = b2[0];

    // ---- gather assignment: slot = edge within tile, cch = 8-float chunk ----
    const int s_slot = t >> 4;        // 0..31
    const int cch    = t & 15;        // 0..15

    // ---- pipeline prologue ----
    int tile = blockIdx.x;
    // z loads for tile (dependent chain tolerated once)
    float4 a0, a1, c0, c1;
    {
        const int e = tile * M_TILE + s_slot;
        const int u = edge[e], v = edge[N_EDGES + e];
        const float* zu = z + (size_t)u * D_IN + cch * 8;
        const float* zv = z + (size_t)v * D_IN + cch * 8;
        a0 = *reinterpret_cast<const float4*>(zu);
        a1 = *reinterpret_cast<const float4*>(zu + 4);
        c0 = *reinterpret_cast<const float4*>(zv);
        c1 = *reinterpret_cast<const float4*>(zv + 4);
    }
    // edge indices for tile+GRID
    int u_n, v_n;
    {
        const int t1 = min(tile + GRID, NTILES - 1);
        const int e1 = t1 * M_TILE + s_slot;
        u_n = edge[e1]; v_n = edge[N_EDGES + e1];
    }

    int  p = 0;
    bool have_prev = false;
    int  prev_base = 0;

    for (; tile < NTILES; tile += GRID) {
        // ---- A: convert current tile's gathered rows -> xbuf[p] ----
        {
            F4H A0{a0}, A1{a1}, C0{c0}, C1{c1};
            unsigned int r0 = pkbf(A0.h[0] * C0.h[0]);
            unsigned int r1 = pkbf(A0.h[1] * C0.h[1]);
            unsigned int r2 = pkbf(A1.h[0] * C1.h[0]);
            unsigned int r3 = pkbf(A1.h[1] * C1.h[1]);
            *reinterpret_cast<uint4*>(&xbuf[p][s_slot * LDS_STRIDE + cch * 8]) =
                make_uint4(r0, r1, r2, r3);
        }
        // ---- B: the single barrier ----
        __syncthreads();

        // ---- C: issue next tile's z loads (indices already resident) +
        //          edge-index loads 2 tiles ahead ----
        {
            const float* zu = z + (size_t)u_n * D_IN + cch * 8;
            const float* zv = z + (size_t)v_n * D_IN + cch * 8;
            a0 = *reinterpret_cast<const float4*>(zu);
            a1 = *reinterpret_cast<const float4*>(zu + 4);
            c0 = *reinterpret_cast<const float4*>(zv);
            c1 = *reinterpret_cast<const float4*>(zv + 4);
        }
        {
            const int t2 = min(tile + 2 * GRID, NTILES - 1);
            const int e2 = t2 * M_TILE + s_slot;
            u_n = edge[e2]; v_n = edge[N_EDGES + e2];
        }

        // ---- E: combine + store PREVIOUS tile (lpart[p^1] sealed by barrier) ----
        if (have_prev) {
            if (t < M_TILE) {
                const int pp = p ^ 1;
                float logit = b2f;
                #pragma unroll
                for (int w = 0; w < 8; ++w) logit += lpart[pp][w][t];
                out[prev_base + t] = __builtin_amdgcn_rcpf(1.0f + __expf(-logit));
            }
        }

        // ---- D: MFMA + epilogue for current tile -> lpart[p] ----
        f32x4 acc[2][2];
        #pragma unroll
        for (int mt = 0; mt < 2; ++mt)
            #pragma unroll
            for (int nt = 0; nt < 2; ++nt)
                acc[mt][nt] = (f32x4){0.f, 0.f, 0.f, 0.f};

        #pragma unroll
        for (int ks = 0; ks < 4; ++ks) {
            bf16x8 af[2];
            #pragma unroll
            for (int mt = 0; mt < 2; ++mt)
                af[mt] = *reinterpret_cast<const bf16x8*>(
                    &xbuf[p][(mt * 16 + nlo) * LDS_STRIDE + ks * 32 + quad * 8]);
            #pragma unroll
            for (int mt = 0; mt < 2; ++mt)
                #pragma unroll
                for (int nt = 0; nt < 2; ++nt)
                    acc[mt][nt] = __builtin_amdgcn_mfma_f32_16x16x32_bf16(
                        af[mt], bfrag[ks][nt], acc[mt][nt], 0, 0, 0);
        }

        // D layout: row = mt*16 + quad*4 + r, col = nlo + 16nt (+32*wave)
        #pragma unroll
        for (int mt = 0; mt < 2; ++mt) {
            #pragma unroll
            for (int pr = 0; pr < 2; ++pr) {
                f32x2 s2 = {0.f, 0.f};
                #pragma unroll
                for (int nt = 0; nt < 2; ++nt) {
                    f32x2 h = {acc[mt][nt][2 * pr]     + b1f[nt],
                               acc[mt][nt][2 * pr + 1] + b1f[nt]};
                    f32x2 m = mish2(h);
                    s2.x += m.x * w2f[nt];
                    s2.y += m.y * w2f[nt];
                }
                float sx = s2.x, sy = s2.y;
                sx += __shfl_xor(sx, 1); sy += __shfl_xor(sy, 1);
                sx += __shfl_xor(sx, 2); sy += __shfl_xor(sy, 2);
                sx += __shfl_xor(sx, 4); sy += __shfl_xor(sy, 4);
                sx += __shfl_xor(sx, 8); sy += __shfl_xor(sy, 8);
                if (nlo == 0) {
                    const int row = mt * 16 + quad * 4 + pr * 2;
                    lpart[p][wave][row]     = sx;
                    lpart[p][wave][row + 1] = sy;
                }
            }
        }

        have_prev = true;
        prev_base = tile * M_TILE;
        p ^= 1;
    }

    // ---- drain: last tile's logits ----
    __syncthreads();
    if (have_prev && t < M_TILE) {
        const int pp = p ^ 1;
        float logit = b2f;
        #pragma unroll
        for (int w = 0; w < 8; ++w) logit += lpart[pp][w][t];
        out[prev_base + t] = __builtin_amdgcn_rcpf(1.0f + __expf(-logit));
    }
}

extern "C" void kernel_launch(void* const* d_in, const int* in_sizes, int n_in,
                              void* d_out, int out_size, void* d_ws, size_t ws_size,
                              hipStream_t stream) {
    const float* z    = (const float*)d_in[0];
    const int*   edge = (const int*)d_in[1];
    const float* W1   = (const float*)d_in[2];
    const float* b1   = (const float*)d_in[3];
    const float* W2   = (const float*)d_in[4];
    const float* b2   = (const float*)d_in[5];
    float* out = (float*)d_out;

    edge_decoder_kernel<<<dim3(GRID), dim3(512), 0, stream>>>(z, edge, W1, b1, W2, b2, out);
}